// Round 4
// baseline (151.776 us; speedup 1.0000x reference)
//
#include <hip/hip_runtime.h>
#include <hip/hip_cooperative_groups.h>
#include <math.h>

namespace cg = cooperative_groups;

// MultiChannelXi: xi[b,t,k,:] = sum_{s<=t} alpha_k^(t-s) h[b,s,:] / Z_{k,t}
// alpha = clip(sigmoid(raw_alpha), 1e-6, 1-1e-6),
// Z_{k,t} = (1 - alpha^(t+1)) / (1 - alpha).
//
// Single cooperative kernel; h chunk staged in LDS (NOT registers — round 2
// spilled 128 VGPRs of h to scratch and ran 3x slower).
//   phase 1 : stream h chunk -> LDS, compute chunk-weighted sums L
//   sync
//   phase 2a: per-group (8 chunks) weighted sums G (first 64 blocks)
//   sync
//   phase 2b: every block builds its entering state from <=15 G + <=7 L
//             (hierarchical — verified correct in round 2)
//   phase 3 : rescan chunk from LDS, normalize, write out (write-BW bound)

namespace {

constexpr int T_LEN  = 4096;
constexpr int D_DIM  = 512;
constexpr int D4     = D_DIM / 4;      // 128 float4 lanes
constexpr int K_CH   = 4;
constexpr int CHUNK  = 32;
constexpr int NCHUNK = T_LEN / CHUNK;  // 128
constexpr int GRP    = 8;
constexpr int NGRP   = NCHUNK / GRP;   // 16

__device__ __forceinline__ float sigmoid_clip(float x) {
    float a = 1.0f / (1.0f + expf(-x));
    return fminf(fmaxf(a, 1e-6f), 1.0f - 1e-6f);
}

__device__ __forceinline__ void fma4(float4& d, float a, const float4& x) {
    d.x = fmaf(a, d.x, x.x);
    d.y = fmaf(a, d.y, x.y);
    d.z = fmaf(a, d.z, x.z);
    d.w = fmaf(a, d.w, x.w);
}

__global__ void __launch_bounds__(128, 2)
ema_fused(const float4* __restrict__ h4,
          const float*  __restrict__ raw_alpha,
          float4* __restrict__ lbuf,   // [B][NCHUNK][K][D4]
          float4* __restrict__ gbuf,   // [B][NGRP][K][D4]
          float4* __restrict__ out4,   // [B][T][K][D4]
          int B)
{
    __shared__ float4 hsm[CHUNK * D4];           // 64 KB: the h chunk

    cg::grid_group grid = cg::this_grid();
    const int c  = blockIdx.x % NCHUNK;
    const int b  = blockIdx.x / NCHUNK;
    const int d4 = threadIdx.x;
    const int t0 = c * CHUNK;

    float al[K_CH], aC[K_CH];
#pragma unroll
    for (int k = 0; k < K_CH; ++k) {
        al[k] = sigmoid_clip(raw_alpha[k]);
        aC[k] = exp2f((float)CHUNK * log2f(al[k]));   // alpha^CHUNK
    }

    // ---- phase 1: h chunk -> LDS; chunk-weighted sums L ----
    {
        const float4* hp = h4 + ((size_t)b * T_LEN + t0) * D4 + d4;
        float4 L[K_CH];
#pragma unroll
        for (int k = 0; k < K_CH; ++k) L[k] = make_float4(0.f, 0.f, 0.f, 0.f);
#pragma unroll 4
        for (int j = 0; j < CHUNK; ++j) {
            const float4 hv = hp[(size_t)j * D4];
            hsm[j * D4 + d4] = hv;
#pragma unroll
            for (int k = 0; k < K_CH; ++k) fma4(L[k], al[k], hv);
        }
#pragma unroll
        for (int k = 0; k < K_CH; ++k)
            lbuf[(((size_t)b * NCHUNK + c) * K_CH + k) * D4 + d4] = L[k];
    }

    grid.sync();

    // ---- phase 2a: group sums G[b][g] = sum_i aC^(GRP-1-i) * L[b][g*GRP+i] ----
    if (blockIdx.x < (unsigned)(B * NGRP)) {
        const int g  = blockIdx.x % NGRP;
        const int bb = blockIdx.x / NGRP;
        float4 G[K_CH];
#pragma unroll
        for (int k = 0; k < K_CH; ++k) G[k] = make_float4(0.f, 0.f, 0.f, 0.f);
        for (int i = 0; i < GRP; ++i) {
            const int cp = g * GRP + i;
#pragma unroll
            for (int k = 0; k < K_CH; ++k) {
                float4 Lv = lbuf[(((size_t)bb * NCHUNK + cp) * K_CH + k) * D4 + d4];
                fma4(G[k], aC[k], Lv);
            }
        }
#pragma unroll
        for (int k = 0; k < K_CH; ++k)
            gbuf[(((size_t)bb * NGRP + g) * K_CH + k) * D4 + d4] = G[k];
    }

    grid.sync();

    // ---- phase 2b: entering state for chunk c (hierarchical prefix) ----
    float4 S[K_CH];
#pragma unroll
    for (int k = 0; k < K_CH; ++k) S[k] = make_float4(0.f, 0.f, 0.f, 0.f);
    {
        const int g = c / GRP;
        float aG[K_CH];
#pragma unroll
        for (int k = 0; k < K_CH; ++k)
            aG[k] = exp2f((float)(CHUNK * GRP) * log2f(al[k]));  // alpha^(C*GRP)
        for (int gp = 0; gp < g; ++gp) {          // whole groups before ours
#pragma unroll
            for (int k = 0; k < K_CH; ++k) {
                float4 Gv = gbuf[(((size_t)b * NGRP + gp) * K_CH + k) * D4 + d4];
                fma4(S[k], aG[k], Gv);
            }
        }
        for (int cp = g * GRP; cp < c; ++cp) {    // leftover chunks in our group
#pragma unroll
            for (int k = 0; k < K_CH; ++k) {
                float4 Lv = lbuf[(((size_t)b * NCHUNK + cp) * K_CH + k) * D4 + d4];
                fma4(S[k], aC[k], Lv);
            }
        }
    }

    // ---- phase 3: rescan from LDS, normalize, store ----
    float om[K_CH], pw[K_CH];
#pragma unroll
    for (int k = 0; k < K_CH; ++k) {
        om[k] = 1.0f - al[k];
        pw[k] = exp2f((float)(t0 + 1) * log2f(al[k]));  // alpha^(t+1) at j=0
    }
    float4* op = out4 + (((size_t)b * T_LEN + t0) * (size_t)K_CH) * D4 + d4;
#pragma unroll 2
    for (int j = 0; j < CHUNK; ++j) {
        const float4 hv = hsm[j * D4 + d4];
#pragma unroll
        for (int k = 0; k < K_CH; ++k) {
            fma4(S[k], al[k], hv);
            const float invZ = om[k] / fmaxf(1.0f - pw[k], 1e-30f);
            float4 o;
            o.x = S[k].x * invZ;
            o.y = S[k].y * invZ;
            o.z = S[k].z * invZ;
            o.w = S[k].w * invZ;
            op[((size_t)j * K_CH + k) * D4] = o;
            pw[k] *= al[k];
        }
    }
}

} // namespace

extern "C" void kernel_launch(void* const* d_in, const int* in_sizes, int n_in,
                              void* d_out, int out_size, void* d_ws, size_t ws_size,
                              hipStream_t stream)
{
    const float4* h4        = (const float4*)d_in[0];
    const float*  raw_alpha = (const float*)d_in[1];
    float4* out4 = (float4*)d_out;

    int B = in_sizes[0] / (T_LEN * D_DIM);  // 4

    float4* lbuf = (float4*)d_ws;                          // 4 MB
    float4* gbuf = lbuf + (size_t)B * NCHUNK * K_CH * D4;  // 512 KB

    void* kargs[] = { (void*)&h4, (void*)&raw_alpha, (void*)&lbuf,
                      (void*)&gbuf, (void*)&out4, (void*)&B };
    hipLaunchCooperativeKernel((void*)ema_fused, dim3(B * NCHUNK), dim3(D4),
                               kargs, 0, stream);
}

// Round 6
// 53.737 us; speedup vs baseline: 2.8245x; 2.8245x over previous
//
#include <hip/hip_runtime.h>
#include <math.h>

// MultiChannelXi: xi[b,t,k,:] = sum_{s<=t} alpha_k^(t-s) h[b,s,:] / Z_{k,t}
// alpha = clip(sigmoid(raw_alpha), 1e-6, 1-1e-6),
// Z_{k,t} = (1 - alpha^(t+1)) / (1 - alpha).
//
// 3-kernel chunked scan, all phases parallel (no serial kernel, no grid.sync):
//   k1: per-chunk weighted sums L[b,c,k,:]        (streams h once, CHUNK=16)
//   kB: per-group sums G[b,g,k,:] over GRP=16 chunks (tiny, L2-resident)
//   k3: hierarchical prefix (<=15 G + <=15 L loads) -> rescan chunk ->
//       normalize -> non-temporal store of out.
// Lessons: r2/r4 fused+grid.sync = 1 wave/SIMD latency trap (151us);
//          r3 flat O(c) prefix = redundant-work trap (78us).

namespace {

constexpr int T_LEN  = 4096;
constexpr int D_DIM  = 512;
constexpr int D4     = D_DIM / 4;      // 128 float4 lanes per row
constexpr int K_CH   = 4;
constexpr int CHUNK  = 16;
constexpr int NCHUNK = T_LEN / CHUNK;  // 256
constexpr int GRP    = 16;
constexpr int NGRP   = NCHUNK / GRP;   // 16

typedef float floatx4 __attribute__((ext_vector_type(4)));  // native vec for NT store

__device__ __forceinline__ float sigmoid_clip(float x) {
    float a = 1.0f / (1.0f + expf(-x));
    return fminf(fmaxf(a, 1e-6f), 1.0f - 1e-6f);
}

__device__ __forceinline__ void fma4(float4& d, float a, const float4& x) {
    d.x = fmaf(a, d.x, x.x);
    d.y = fmaf(a, d.y, x.y);
    d.z = fmaf(a, d.z, x.z);
    d.w = fmaf(a, d.w, x.w);
}

__device__ __forceinline__ void nt_store4(float4* p, const float4& v) {
    floatx4 nv;
    nv.x = v.x; nv.y = v.y; nv.z = v.z; nv.w = v.w;
    __builtin_nontemporal_store(nv, reinterpret_cast<floatx4*>(p));
}

// k1: L[b,c,k,:] = sum_{j=0..C-1} alpha_k^(C-1-j) * h[b, c*C+j, :]
__global__ void __launch_bounds__(128)
ema_chunk_sums(const float4* __restrict__ h4,
               const float*  __restrict__ raw_alpha,
               float4* __restrict__ lbuf) {
    const int c  = blockIdx.x % NCHUNK;
    const int b  = blockIdx.x / NCHUNK;
    const int d4 = threadIdx.x;

    float al[K_CH];
#pragma unroll
    for (int k = 0; k < K_CH; ++k) al[k] = sigmoid_clip(raw_alpha[k]);

    float4 acc[K_CH];
#pragma unroll
    for (int k = 0; k < K_CH; ++k) acc[k] = make_float4(0.f, 0.f, 0.f, 0.f);

    const float4* hp = h4 + ((size_t)b * T_LEN + (size_t)c * CHUNK) * D4 + d4;
#pragma unroll 4
    for (int j = 0; j < CHUNK; ++j) {
        const float4 hv = hp[(size_t)j * D4];
#pragma unroll
        for (int k = 0; k < K_CH; ++k) fma4(acc[k], al[k], hv);
    }
#pragma unroll
    for (int k = 0; k < K_CH; ++k)
        lbuf[(((size_t)b * NCHUNK + c) * K_CH + k) * D4 + d4] = acc[k];
}

// kB: G[b,g,k,:] = sum_{i=0..GRP-1} aC^(GRP-1-i) * L[b, g*GRP+i, k, :]
__global__ void __launch_bounds__(128)
ema_group_sums(const float*  __restrict__ raw_alpha,
               const float4* __restrict__ lbuf,
               float4* __restrict__ gbuf) {
    const int g  = blockIdx.x % NGRP;
    const int b  = blockIdx.x / NGRP;
    const int d4 = threadIdx.x;

    float aC[K_CH];
#pragma unroll
    for (int k = 0; k < K_CH; ++k) {
        const float a = sigmoid_clip(raw_alpha[k]);
        aC[k] = exp2f((float)CHUNK * log2f(a));
    }

    float4 G[K_CH];
#pragma unroll
    for (int k = 0; k < K_CH; ++k) G[k] = make_float4(0.f, 0.f, 0.f, 0.f);

    const float4* lp = lbuf + (((size_t)b * NCHUNK + (size_t)g * GRP) * K_CH) * D4 + d4;
#pragma unroll 4
    for (int i = 0; i < GRP; ++i) {
#pragma unroll
        for (int k = 0; k < K_CH; ++k) {
            const float4 Lv = lp[((size_t)i * K_CH + k) * D4];
            fma4(G[k], aC[k], Lv);
        }
    }
#pragma unroll
    for (int k = 0; k < K_CH; ++k)
        gbuf[(((size_t)b * NGRP + g) * K_CH + k) * D4 + d4] = G[k];
}

// k3: hierarchical prefix -> rescan chunk -> normalize -> NT store.
__global__ void __launch_bounds__(128)
ema_apply(const float4* __restrict__ h4,
          const float*  __restrict__ raw_alpha,
          const float4* __restrict__ lbuf,
          const float4* __restrict__ gbuf,
          float4* __restrict__ out4) {
    // reverse c: long-prefix blocks first (tail balance)
    const int c  = (NCHUNK - 1) - (blockIdx.x % NCHUNK);
    const int b  = blockIdx.x / NCHUNK;
    const int d4 = threadIdx.x;
    const int t0 = c * CHUNK;

    float al[K_CH], aC[K_CH], aG[K_CH];
#pragma unroll
    for (int k = 0; k < K_CH; ++k) {
        al[k] = sigmoid_clip(raw_alpha[k]);
        const float l2a = log2f(al[k]);
        aC[k] = exp2f((float)CHUNK * l2a);          // alpha^CHUNK
        aG[k] = exp2f((float)(CHUNK * GRP) * l2a);  // alpha^(CHUNK*GRP)
    }

    // ---- entering state via hierarchy: whole groups, then leftover chunks ----
    float4 S[K_CH];
#pragma unroll
    for (int k = 0; k < K_CH; ++k) S[k] = make_float4(0.f, 0.f, 0.f, 0.f);
    {
        const int g = c / GRP;
        const float4* gp = gbuf + ((size_t)b * NGRP * K_CH) * D4 + d4;
#pragma unroll 4
        for (int gq = 0; gq < g; ++gq) {
#pragma unroll
            for (int k = 0; k < K_CH; ++k) {
                const float4 Gv = gp[((size_t)gq * K_CH + k) * D4];
                fma4(S[k], aG[k], Gv);
            }
        }
        const float4* lp = lbuf + ((size_t)b * NCHUNK * K_CH) * D4 + d4;
#pragma unroll 4
        for (int cp = g * GRP; cp < c; ++cp) {
#pragma unroll
            for (int k = 0; k < K_CH; ++k) {
                const float4 Lv = lp[((size_t)cp * K_CH + k) * D4];
                fma4(S[k], aC[k], Lv);
            }
        }
    }

    // ---- rescan chunk, normalize, non-temporal store ----
    float om[K_CH], pw[K_CH];
#pragma unroll
    for (int k = 0; k < K_CH; ++k) {
        om[k] = 1.0f - al[k];
        pw[k] = exp2f((float)(t0 + 1) * log2f(al[k]));  // alpha^(t+1) at j=0
    }

    const float4* hp = h4 + ((size_t)b * T_LEN + t0) * D4 + d4;
    float4* op = out4 + (((size_t)b * T_LEN + t0) * (size_t)K_CH) * D4 + d4;

#pragma unroll 2
    for (int j = 0; j < CHUNK; ++j) {
        const float4 hv = hp[(size_t)j * D4];
#pragma unroll
        for (int k = 0; k < K_CH; ++k) {
            fma4(S[k], al[k], hv);
            const float invZ = om[k] / fmaxf(1.0f - pw[k], 1e-30f);
            float4 o;
            o.x = S[k].x * invZ;
            o.y = S[k].y * invZ;
            o.z = S[k].z * invZ;
            o.w = S[k].w * invZ;
            nt_store4(&op[((size_t)j * K_CH + k) * D4], o);
            pw[k] *= al[k];
        }
    }
}

} // namespace

extern "C" void kernel_launch(void* const* d_in, const int* in_sizes, int n_in,
                              void* d_out, int out_size, void* d_ws, size_t ws_size,
                              hipStream_t stream)
{
    const float4* h4        = (const float4*)d_in[0];
    const float*  raw_alpha = (const float*)d_in[1];
    float4* out4 = (float4*)d_out;

    const int B = in_sizes[0] / (T_LEN * D_DIM);  // 4

    float4* lbuf = (float4*)d_ws;                          // B*256*4*128 float4 = 8 MB
    float4* gbuf = lbuf + (size_t)B * NCHUNK * K_CH * D4;  // B*16*4*128 float4 = 512 KB

    const dim3 blk(D4);  // 128 threads

    hipLaunchKernelGGL(ema_chunk_sums, dim3(B * NCHUNK), blk, 0, stream,
                       h4, raw_alpha, lbuf);
    hipLaunchKernelGGL(ema_group_sums, dim3(B * NGRP), blk, 0, stream,
                       raw_alpha, lbuf, gbuf);
    hipLaunchKernelGGL(ema_apply, dim3(B * NCHUNK), blk, 0, stream,
                       h4, raw_alpha, lbuf, gbuf, out4);
}

// Round 7
// 51.742 us; speedup vs baseline: 2.9333x; 1.0386x over previous
//
#include <hip/hip_runtime.h>
#include <math.h>

// MultiChannelXi: xi[b,t,k,:] = sum_{s<=t} alpha_k^(t-s) h[b,s,:] / Z_{k,t}
// alpha = clip(sigmoid(raw_alpha), 1e-6, 1-1e-6),
// Z_{k,t} = (1 - alpha^(t+1)) / (1 - alpha).
//
// 4-kernel chunked scan; every kernel fully parallel, k3 is pure streaming:
//   k1: per-chunk weighted sums L[b,c,k,:]   (CHUNK=32 — round-1 verified)
//   kB: per-group sums G[b,g,k,:] (GRP=8 chunks)           — tiny
//   kP: per-chunk entering state P[b,c,k,:] from <=15 G + <=7 L (Horner,
//       L2-resident) — replaces round-1's 13-15us serial scan with ~3us
//   k3: S=P[b,c]; rescan 32 rows; normalize; store  (round-1's exact k3)
// Lessons: prefix work inside k3 = latency trap (r3: +28us, r6: +15us);
//          fused grid.sync = 1 wave/SIMD trap (r2/r4: 151us).

namespace {

constexpr int T_LEN  = 4096;
constexpr int D_DIM  = 512;
constexpr int D4     = D_DIM / 4;      // 128 float4 lanes per row
constexpr int K_CH   = 4;
constexpr int CHUNK  = 32;
constexpr int NCHUNK = T_LEN / CHUNK;  // 128
constexpr int GRP    = 8;
constexpr int NGRP   = NCHUNK / GRP;   // 16

__device__ __forceinline__ float sigmoid_clip(float x) {
    float a = 1.0f / (1.0f + expf(-x));
    return fminf(fmaxf(a, 1e-6f), 1.0f - 1e-6f);
}

__device__ __forceinline__ void fma4(float4& d, float a, const float4& x) {
    d.x = fmaf(a, d.x, x.x);
    d.y = fmaf(a, d.y, x.y);
    d.z = fmaf(a, d.z, x.z);
    d.w = fmaf(a, d.w, x.w);
}

// k1: L[b,c,k,:] = sum_{j=0..C-1} alpha_k^(C-1-j) * h[b, c*C+j, :]
__global__ void __launch_bounds__(128)
ema_chunk_sums(const float4* __restrict__ h4,
               const float*  __restrict__ raw_alpha,
               float4* __restrict__ lbuf) {
    const int c  = blockIdx.x % NCHUNK;
    const int b  = blockIdx.x / NCHUNK;
    const int d4 = threadIdx.x;

    float al[K_CH];
#pragma unroll
    for (int k = 0; k < K_CH; ++k) al[k] = sigmoid_clip(raw_alpha[k]);

    float4 acc[K_CH];
#pragma unroll
    for (int k = 0; k < K_CH; ++k) acc[k] = make_float4(0.f, 0.f, 0.f, 0.f);

    const float4* hp = h4 + ((size_t)b * T_LEN + (size_t)c * CHUNK) * D4 + d4;
#pragma unroll 4
    for (int j = 0; j < CHUNK; ++j) {
        const float4 hv = hp[(size_t)j * D4];
#pragma unroll
        for (int k = 0; k < K_CH; ++k) fma4(acc[k], al[k], hv);
    }
#pragma unroll
    for (int k = 0; k < K_CH; ++k)
        lbuf[(((size_t)b * NCHUNK + c) * K_CH + k) * D4 + d4] = acc[k];
}

// kB: G[b,g,k,:] = Horner over the group's 8 L's with ratio aC = alpha^CHUNK
__global__ void __launch_bounds__(128)
ema_group_sums(const float*  __restrict__ raw_alpha,
               const float4* __restrict__ lbuf,
               float4* __restrict__ gbuf) {
    const int g  = blockIdx.x % NGRP;
    const int b  = blockIdx.x / NGRP;
    const int d4 = threadIdx.x;

    float aC[K_CH];
#pragma unroll
    for (int k = 0; k < K_CH; ++k) {
        const float a = sigmoid_clip(raw_alpha[k]);
        aC[k] = exp2f((float)CHUNK * log2f(a));
    }

    float4 G[K_CH];
#pragma unroll
    for (int k = 0; k < K_CH; ++k) G[k] = make_float4(0.f, 0.f, 0.f, 0.f);

    const float4* lp = lbuf + (((size_t)b * NCHUNK + (size_t)g * GRP) * K_CH) * D4 + d4;
#pragma unroll
    for (int i = 0; i < GRP; ++i) {
#pragma unroll
        for (int k = 0; k < K_CH; ++k) {
            const float4 Lv = lp[((size_t)i * K_CH + k) * D4];
            fma4(G[k], aC[k], Lv);
        }
    }
#pragma unroll
    for (int k = 0; k < K_CH; ++k)
        gbuf[(((size_t)b * NGRP + g) * K_CH + k) * D4 + d4] = G[k];
}

// kP: P[b,c,k,:] = state entering chunk c (Horner over <=15 G then <=7 L)
__global__ void __launch_bounds__(128)
ema_chunk_prefix(const float*  __restrict__ raw_alpha,
                 const float4* __restrict__ lbuf,
                 const float4* __restrict__ gbuf,
                 float4* __restrict__ pbuf) {
    const int c  = blockIdx.x % NCHUNK;
    const int b  = blockIdx.x / NCHUNK;
    const int d4 = threadIdx.x;

    float aC[K_CH], aG[K_CH];
#pragma unroll
    for (int k = 0; k < K_CH; ++k) {
        const float a   = sigmoid_clip(raw_alpha[k]);
        const float l2a = log2f(a);
        aC[k] = exp2f((float)CHUNK * l2a);          // alpha^CHUNK
        aG[k] = exp2f((float)(CHUNK * GRP) * l2a);  // alpha^(CHUNK*GRP)
    }

    float4 S[K_CH];
#pragma unroll
    for (int k = 0; k < K_CH; ++k) S[k] = make_float4(0.f, 0.f, 0.f, 0.f);

    const int g = c / GRP;
    const float4* gp = gbuf + ((size_t)b * NGRP * K_CH) * D4 + d4;
    for (int gq = 0; gq < g; ++gq) {
#pragma unroll
        for (int k = 0; k < K_CH; ++k) {
            const float4 Gv = gp[((size_t)gq * K_CH + k) * D4];
            fma4(S[k], aG[k], Gv);
        }
    }
    const float4* lp = lbuf + ((size_t)b * NCHUNK * K_CH) * D4 + d4;
    for (int cp = g * GRP; cp < c; ++cp) {
#pragma unroll
        for (int k = 0; k < K_CH; ++k) {
            const float4 Lv = lp[((size_t)cp * K_CH + k) * D4];
            fma4(S[k], aC[k], Lv);
        }
    }
#pragma unroll
    for (int k = 0; k < K_CH; ++k)
        pbuf[(((size_t)b * NCHUNK + c) * K_CH + k) * D4 + d4] = S[k];
}

// k3: S = P[b,c]; rescan chunk; normalize; store.  (round-1's exact k3)
__global__ void __launch_bounds__(128)
ema_apply(const float4* __restrict__ h4,
          const float*  __restrict__ raw_alpha,
          const float4* __restrict__ pbuf,
          float4* __restrict__ out4) {
    const int c  = blockIdx.x % NCHUNK;
    const int b  = blockIdx.x / NCHUNK;
    const int d4 = threadIdx.x;
    const int t0 = c * CHUNK;

    float al[K_CH], om[K_CH], pw[K_CH];
#pragma unroll
    for (int k = 0; k < K_CH; ++k) {
        const float a = sigmoid_clip(raw_alpha[k]);
        al[k] = a;
        om[k] = 1.0f - a;
        pw[k] = exp2f((float)(t0 + 1) * log2f(a));  // alpha^(t+1) at j=0
    }

    float4 S[K_CH];
#pragma unroll
    for (int k = 0; k < K_CH; ++k)
        S[k] = pbuf[(((size_t)b * NCHUNK + c) * K_CH + k) * D4 + d4];

    const float4* hp = h4 + ((size_t)b * T_LEN + t0) * D4 + d4;
    float4* op = out4 + (((size_t)b * T_LEN + t0) * (size_t)K_CH) * D4 + d4;

#pragma unroll 2
    for (int j = 0; j < CHUNK; ++j) {
        const float4 hv = hp[(size_t)j * D4];
#pragma unroll
        for (int k = 0; k < K_CH; ++k) {
            fma4(S[k], al[k], hv);
            const float invZ = om[k] / fmaxf(1.0f - pw[k], 1e-30f);
            float4 o;
            o.x = S[k].x * invZ;
            o.y = S[k].y * invZ;
            o.z = S[k].z * invZ;
            o.w = S[k].w * invZ;
            op[((size_t)j * K_CH + k) * D4] = o;
            pw[k] *= al[k];
        }
    }
}

} // namespace

extern "C" void kernel_launch(void* const* d_in, const int* in_sizes, int n_in,
                              void* d_out, int out_size, void* d_ws, size_t ws_size,
                              hipStream_t stream)
{
    const float4* h4        = (const float4*)d_in[0];
    const float*  raw_alpha = (const float*)d_in[1];
    float4* out4 = (float4*)d_out;

    const int B = in_sizes[0] / (T_LEN * D_DIM);  // 4

    float4* lbuf = (float4*)d_ws;                          // B*128*4*128 float4 = 4 MB
    float4* gbuf = lbuf + (size_t)B * NCHUNK * K_CH * D4;  // B*16*4*128  float4 = 512 KB
    float4* pbuf = gbuf + (size_t)B * NGRP   * K_CH * D4;  // B*128*4*128 float4 = 4 MB

    const dim3 blk(D4);  // 128 threads

    hipLaunchKernelGGL(ema_chunk_sums, dim3(B * NCHUNK), blk, 0, stream,
                       h4, raw_alpha, lbuf);
    hipLaunchKernelGGL(ema_group_sums, dim3(B * NGRP), blk, 0, stream,
                       raw_alpha, lbuf, gbuf);
    hipLaunchKernelGGL(ema_chunk_prefix, dim3(B * NCHUNK), blk, 0, stream,
                       raw_alpha, lbuf, gbuf, pbuf);
    hipLaunchKernelGGL(ema_apply, dim3(B * NCHUNK), blk, 0, stream,
                       h4, raw_alpha, pbuf, out4);
}